// Round 5
// baseline (6332.614 us; speedup 1.0000x reference)
//
#include <hip/hip_runtime.h>
#include <math.h>

#define S 512
#define B 64
#define I 1024
#define HD 1024
#define G4 (4*HD)
#define NB 256
#define ARRS 16   // ints per arrival-counter slot (64B line)
#define EPS 16    // ints per epoch slot (64B line)

typedef _Float16 half8 __attribute__((ext_vector_type(8)));
typedef float floatx4 __attribute__((ext_vector_type(4)));
typedef float f32x4 __attribute__((ext_vector_type(4)));
typedef unsigned uint4v __attribute__((ext_vector_type(4)));
typedef unsigned long long u64x2 __attribute__((ext_vector_type(2)));

// ---------- prep kernels ----------

__global__ void cast_f32_to_f16(const float* __restrict__ src,
                                _Float16* __restrict__ dst, long n8) {
    long i = (long)blockIdx.x * blockDim.x + threadIdx.x;
    if (i >= n8) return;
    const f32x4* s = (const f32x4*)src + i * 2;
    f32x4 a = s[0], b = s[1];
    half8 h;
    h[0] = (_Float16)a[0]; h[1] = (_Float16)a[1];
    h[2] = (_Float16)a[2]; h[3] = (_Float16)a[3];
    h[4] = (_Float16)b[0]; h[5] = (_Float16)b[1];
    h[6] = (_Float16)b[2]; h[7] = (_Float16)b[3];
    *((half8*)dst + i) = h;
}

__global__ void init_state(const float* __restrict__ h0,
                           const float* __restrict__ bi, const float* __restrict__ bh,
                           _Float16* __restrict__ hb0, float* __restrict__ bsum,
                           int* __restrict__ arr, int* __restrict__ epoch) {
    int i = blockIdx.x * blockDim.x + threadIdx.x;
    if (i < B * HD) hb0[i] = (_Float16)h0[i];
    if (i < G4) bsum[i] = bi[i] + bh[i];
    if (i < 32) arr[i * ARRS] = 0;
    if (i < 256) epoch[i * EPS] = 0;
}

// ---------- persistent recurrent kernel ----------
// 256 blocks x 256 threads, 1 block/CU (cooperative). Block m: rg=m>>1 owns
// hidden units [rg*8, rg*8+8); bg=m&1 owns batches [bg*32, +32).
// Waves: rt=w>>1 (row tile), bt=w&1 (batch tile). Weights in LDS in
// MFMA-fragment order (lane-dense 16B -> conflict-free). D lane l:
// batch=16*bt+(l&15), j=rg*8+rt*4+(l>>4), all 4 gates in acc registers;
// c stays in a register all 512 steps.
// Barrier (decontended): arrivals -> 32 counter lines (8 blocks each);
// block 0 wave 0 polls all 32 in parallel, then fans out per-block epoch
// words on 256 private lines; each block polls only its own line.
// h handoff: u64 atomic-exchange writes (RMW at L3), u64 relaxed-agent
// atomic loads (sc1, L2 bypass), 3-slot ring.

__global__ __launch_bounds__(256, 1) void lstm_persistent(
    const _Float16* __restrict__ xb,
    const _Float16* __restrict__ Wib,
    const _Float16* __restrict__ Whb,
    const float*    __restrict__ bsum,
    const float*    __restrict__ c0,
    _Float16* __restrict__ hr0,
    _Float16* __restrict__ hr1,
    _Float16* __restrict__ hr2,
    float*          __restrict__ out,
    int*            __restrict__ arr,
    int*            __restrict__ epoch)
{
    __shared__ _Float16 fragWi[32768];   // 64 KB
    __shared__ _Float16 fragWh[32768];   // 64 KB

    const int m = blockIdx.x;
    const int rg = m >> 1;
    const int bg = m & 1;
    const int tid = threadIdx.x;
    const int l = tid & 63, w = tid >> 6;
    const int rt = w >> 1, bt = w & 1;

    // Stage 32 local W rows of Wi and Wh into fragment-order LDS (once).
    for (int idx = tid; idx < 32 * 128; idx += 256) {
        int r_loc = idx >> 7;
        int ch = idx & 127;
        int rtt = r_loc >> 4, a = r_loc & 15;
        int kstep = ch >> 2, sub = ch & 3;
        int lane = sub * 16 + a;
        int grow = (r_loc & 3) * HD + (rg * 8 + (r_loc >> 2));
        int dst = rtt * 16384 + kstep * 512 + lane * 8;
        *(half8*)&fragWi[dst] = *(const half8*)&Wib[(size_t)grow * I + ch * 8];
        *(half8*)&fragWh[dst] = *(const half8*)&Whb[(size_t)grow * HD + ch * 8];
    }

    const int bq = bg * 32 + bt * 16 + (l & 15);
    const int jq = rg * 8 + rt * 4;
    const int j  = jq + (l >> 4);
    const int kq = (l >> 4) * 8;
    const int fbase = rt * 16384 + l * 8;

    const float b0 = bsum[j];
    const float b1 = bsum[HD + j];
    const float b2 = bsum[2 * HD + j];
    const float b3 = bsum[3 * HD + j];
    const size_t cix = (size_t)bq * HD + j;
    float c = c0[cix];

    __syncthreads();   // weights staged

    int tm = 0;   // t % 3
    for (int t = 0; t < S; ++t) {
        // ---- block 0: discover arrivals of step t-1, then broadcast ----
        if (t > 0 && m == 0) {
            if (w == 0) {
                int* ap = arr + (l & 31) * ARRS;
                const int target = 8 * t;
                while (!__all(__hip_atomic_load(ap, __ATOMIC_RELAXED,
                                                __HIP_MEMORY_SCOPE_AGENT) >= target))
                    __builtin_amdgcn_s_sleep(1);
            }
            __syncthreads();
            __hip_atomic_store(epoch + tid * EPS, t, __ATOMIC_RELAXED,
                               __HIP_MEMORY_SCOPE_AGENT);   // fire & forget
        }

        // ---- x-projection chain (barrier-independent) ----
        const uint4v* xr = (const uint4v*)(xb + ((size_t)t * B + bq) * I + kq);
        floatx4 accx = {0.f, 0.f, 0.f, 0.f};
        #pragma unroll
        for (int kk = 0; kk < 32; ++kk) {
            half8 ax = *(const half8*)&fragWi[fbase + kk * 512];
            half8 bx = __builtin_bit_cast(half8, xr[kk * 4]);
            accx = __builtin_amdgcn_mfma_f32_16x16x32_f16(ax, bx, accx, 0, 0, 0);
        }

        // ---- consumers: poll private epoch line ----
        if (t > 0 && m != 0) {
            if (tid == 0) {
                int* ep = epoch + m * EPS;
                while (__hip_atomic_load(ep, __ATOMIC_RELAXED,
                                         __HIP_MEMORY_SCOPE_AGENT) < t)
                    __builtin_amdgcn_s_sleep(1);
            }
            __syncthreads();
            asm volatile("" ::: "memory");
        }

        // ---- h chain: agent-coherent u64 loads (L2 bypass) ----
        const _Float16* hb_r = (tm == 0) ? hr0 : (tm == 1) ? hr1 : hr2;
        const unsigned long long* hquad =
            (const unsigned long long*)hb_r + ((size_t)bq * HD + kq) / 4;
        floatx4 acch = {0.f, 0.f, 0.f, 0.f};
        #pragma unroll
        for (int kk = 0; kk < 32; ++kk) {
            unsigned long long q0 = __hip_atomic_load(hquad + kk * 8,
                __ATOMIC_RELAXED, __HIP_MEMORY_SCOPE_AGENT);
            unsigned long long q1 = __hip_atomic_load(hquad + kk * 8 + 1,
                __ATOMIC_RELAXED, __HIP_MEMORY_SCOPE_AGENT);
            u64x2 hv; hv.x = q0; hv.y = q1;
            half8 bh = __builtin_bit_cast(half8, hv);
            half8 ah = *(const half8*)&fragWh[fbase + kk * 512];
            acch = __builtin_amdgcn_mfma_f32_16x16x32_f16(ah, bh, acch, 0, 0, 0);
        }

        // ---- gates ----
        float pi = accx[0] + acch[0] + b0;
        float pf = accx[1] + acch[1] + b1;
        float po = accx[2] + acch[2] + b2;
        float pg = accx[3] + acch[3] + b3;

        float ig = 1.f / (1.f + __expf(-pi));
        float fg = 1.f / (1.f + __expf(-pf));
        float og = 1.f / (1.f + __expf(-po));
        float gg = 1.f - 2.f / (__expf(2.f * pg) + 1.f);

        c = c * fg + ig * gg;
        float th = 1.f - 2.f / (__expf(2.f * c) + 1.f);
        float ht = og * th;

        if (t < S - 1) {
            // ---- h ring write: pack quad to u64, one atomic exchange ----
            unsigned hb16 = (unsigned)__builtin_bit_cast(unsigned short, (_Float16)ht);
            unsigned p16 = (unsigned)__shfl_xor((int)hb16, 16);
            unsigned w0 = hb16 | (p16 << 16);
            unsigned long long p32 = (unsigned)__shfl_xor((int)w0, 32);
            unsigned long long w64 = (unsigned long long)w0 | (p32 << 32);
            _Float16* hb_w = (tm == 0) ? hr1 : (tm == 1) ? hr2 : hr0;
            if ((l >> 4) == 0) {
                unsigned long long* dst =
                    (unsigned long long*)hb_w + ((size_t)bq * HD + jq) / 4;
                __hip_atomic_exchange(dst, w64, __ATOMIC_RELAXED,
                                      __HIP_MEMORY_SCOPE_AGENT);
            }
            asm volatile("s_waitcnt vmcnt(0)" ::: "memory");  // h swaps at L3
            __syncthreads();                                   // whole block done
            if (tid == 0)
                __hip_atomic_fetch_add(arr + (m >> 3) * ARRS, 1,
                                       __ATOMIC_RELAXED, __HIP_MEMORY_SCOPE_AGENT);
            asm volatile("" ::: "memory");
        }

        // ---- out store AFTER arrive: off the barrier critical path ----
        float v1 = __shfl_xor(ht, 16);
        float v2 = __shfl_xor(ht, 32);
        float v3 = __shfl_xor(ht, 48);
        if ((l >> 4) == 0) {
            f32x4 o = {ht, v1, v2, v3};
            *(f32x4*)&out[((size_t)t * B + bq) * HD + jq] = o;
        }
        if (t == S - 1) {
            out[(size_t)S * B * HD + cix] = ht;                   // h_f
            out[(size_t)S * B * HD + (size_t)B * HD + cix] = c;   // c_f
        }

        tm = (tm == 2) ? 0 : tm + 1;
    }
}

// ---------- launch ----------

extern "C" void kernel_launch(void* const* d_in, const int* in_sizes, int n_in,
                              void* d_out, int out_size, void* d_ws, size_t ws_size,
                              hipStream_t stream) {
    const float* x  = (const float*)d_in[0];
    const float* h0 = (const float*)d_in[1];
    const float* c0 = (const float*)d_in[2];
    const float* Wi = (const float*)d_in[3];
    const float* bi = (const float*)d_in[4];
    const float* Wh = (const float*)d_in[5];
    const float* bh = (const float*)d_in[6];
    float* out = (float*)d_out;

    char* p = (char*)d_ws;
    _Float16* xb  = (_Float16*)p; p += (size_t)S * B * I * 2;
    _Float16* Wib = (_Float16*)p; p += (size_t)G4 * I * 2;
    _Float16* Whb = (_Float16*)p; p += (size_t)G4 * HD * 2;
    _Float16* hr0 = (_Float16*)p; p += (size_t)B * HD * 2;
    _Float16* hr1 = (_Float16*)p; p += (size_t)B * HD * 2;
    _Float16* hr2 = (_Float16*)p; p += (size_t)B * HD * 2;
    float* bsum   = (float*)p;    p += (size_t)G4 * 4;
    int* arr      = (int*)p;      p += 32 * ARRS * 4;
    int* epoch    = (int*)p;      p += 256 * EPS * 4;

    long nx8 = (long)S * B * I / 8;
    cast_f32_to_f16<<<(int)((nx8 + 255) / 256), 256, 0, stream>>>(x, xb, nx8);
    long nw8 = (long)G4 * I / 8;
    cast_f32_to_f16<<<(int)((nw8 + 255) / 256), 256, 0, stream>>>(Wi, Wib, nw8);
    cast_f32_to_f16<<<(int)((nw8 + 255) / 256), 256, 0, stream>>>(Wh, Whb, nw8);
    init_state<<<(B * HD + 255) / 256, 256, 0, stream>>>(h0, bi, bh, hr0, bsum,
                                                         arr, epoch);

    const float* c0p = c0;
    void* args[] = {(void*)&xb, (void*)&Wib, (void*)&Whb, (void*)&bsum,
                    (void*)&c0p, (void*)&hr0, (void*)&hr1, (void*)&hr2,
                    (void*)&out, (void*)&arr, (void*)&epoch};
    hipLaunchCooperativeKernel((const void*)lstm_persistent, dim3(NB), dim3(256),
                               args, 0, stream);
}

// Round 8
// 5448.889 us; speedup vs baseline: 1.1622x; 1.1622x over previous
//
#include <hip/hip_runtime.h>
#include <math.h>

#define S 512
#define B 64
#define I 1024
#define HD 1024
#define G4 (4*HD)
#define NB 256
#define ARRS 16   // ints per arrival-counter slot (64B line)

typedef _Float16 half8 __attribute__((ext_vector_type(8)));
typedef float floatx4 __attribute__((ext_vector_type(4)));
typedef float f32x4 __attribute__((ext_vector_type(4)));
typedef unsigned uint4v __attribute__((ext_vector_type(4)));
typedef unsigned long long u64x2 __attribute__((ext_vector_type(2)));

// ---------- prep kernels ----------

__global__ void cast_f32_to_f16(const float* __restrict__ src,
                                _Float16* __restrict__ dst, long n8) {
    long i = (long)blockIdx.x * blockDim.x + threadIdx.x;
    if (i >= n8) return;
    const f32x4* s = (const f32x4*)src + i * 2;
    f32x4 a = s[0], b = s[1];
    half8 h;
    h[0] = (_Float16)a[0]; h[1] = (_Float16)a[1];
    h[2] = (_Float16)a[2]; h[3] = (_Float16)a[3];
    h[4] = (_Float16)b[0]; h[5] = (_Float16)b[1];
    h[6] = (_Float16)b[2]; h[7] = (_Float16)b[3];
    *((half8*)dst + i) = h;
}

__global__ void init_state(const float* __restrict__ h0,
                           const float* __restrict__ bi, const float* __restrict__ bh,
                           _Float16* __restrict__ hb0, float* __restrict__ bsum,
                           int* __restrict__ arr) {
    int i = blockIdx.x * blockDim.x + threadIdx.x;
    if (i < B * HD) hb0[i] = (_Float16)h0[i];
    if (i < G4) bsum[i] = bi[i] + bh[i];
    if (i < 32) arr[i * ARRS] = 0;
}

// ---------- persistent recurrent kernel ----------
// 256 blocks x 256 threads, 1 block/CU. Block m: rg=m>>1 owns hidden units
// [rg*8,+8); bg=m&1 owns batches [bg*32,+32). Waves rt=w>>1, bt=w&1.
// Wi fragments in 128 VGPRs/lane; Wh fragments in LDS; h staged once per
// block per step via 32 batch-issued agent-atomic u64 loads into LDS
// fragment layout; accx(t+1) computed between arrive and poll (8-deep
// chunked x loads: latency hides under the poll wait; keeps peak VGPR low
// -- R3/R6/R7 lesson: VGPR>256 => cooperative launch silently rejected,
// kernel never runs, output stays zeroed).
// RELEASE ORDER (R5-proven): exchange -> s_waitcnt vmcnt(0) -> __syncthreads
// -> arrive; out-store strictly AFTER the arrive.
// h handoff: u64 atomic-exchange writes (RMW at L3), u64 relaxed-agent
// atomic loads (sc1, L2 bypass), 3-slot ring, 32-line arrival counters.

__global__ __launch_bounds__(256, 1) void lstm_persistent(
    const _Float16* __restrict__ xb,
    const _Float16* __restrict__ Wib,
    const _Float16* __restrict__ Whb,
    const float*    __restrict__ bsum,
    const float*    __restrict__ c0,
    _Float16* __restrict__ hr0,
    _Float16* __restrict__ hr1,
    _Float16* __restrict__ hr2,
    float*          __restrict__ out,
    int*            __restrict__ arr)
{
    __shared__ alignas(16) _Float16 fragWh[32768];  // 64 KB
    __shared__ alignas(16) _Float16 hfrag[32768];   // 64 KB

    const int m = blockIdx.x;
    const int rg = m >> 1;
    const int bg = m & 1;
    const int tid = threadIdx.x;
    const int l = tid & 63, w = tid >> 6;
    const int rt = w >> 1, bt = w & 1;

    // ---- stage Wh fragments into LDS (once; verified map) ----
    for (int idx = tid; idx < 32 * 128; idx += 256) {
        int r_loc = idx >> 7;
        int ch = idx & 127;
        int rtt = r_loc >> 4, a = r_loc & 15;
        int kstep = ch >> 2, sub = ch & 3;
        int lane = sub * 16 + a;
        int grow = (r_loc & 3) * HD + (rg * 8 + (r_loc >> 2));
        int dst = rtt * 16384 + kstep * 512 + lane * 8;
        *(half8*)&fragWh[dst] = *(const half8*)&Whb[(size_t)grow * HD + ch * 8];
    }

    // ---- Wi fragments into registers (lane-private, read-only) ----
    uint4v wif[32];
    {
        int a = l & 15;
        int r_loc = rt * 16 + a;
        int grow = (r_loc & 3) * HD + (rg * 8 + (r_loc >> 2));
        const _Float16* wrow = Wib + (size_t)grow * I + (l >> 4) * 8;
        #pragma unroll
        for (int kk = 0; kk < 32; ++kk)
            wif[kk] = *(const uint4v*)(wrow + kk * 32);
    }

    const int bq = bg * 32 + bt * 16 + (l & 15);
    const int jq = rg * 8 + rt * 4;
    const int j  = jq + (l >> 4);
    const float b0 = bsum[j];
    const float b1 = bsum[HD + j];
    const float b2 = bsum[2 * HD + j];
    const float b3 = bsum[3 * HD + j];
    const size_t cix = (size_t)bq * HD + j;
    float c = c0[cix];

    __syncthreads();   // Wh staged

    // ---- prologue: stage h0 into hfrag; compute accx(0) ----
    {
        unsigned long long hld[32];
        #pragma unroll
        for (int cc = 0; cc < 16; ++cc) {
            int e = w + cc * 4;
            int kk = e & 31, btc = e >> 5;
            int bq_s = bg * 32 + btc * 16 + (l & 15);
            int k0 = (l >> 4) * 8 + kk * 32;
            const unsigned long long* sp =
                (const unsigned long long*)hr0 + ((size_t)bq_s * HD + k0) / 4;
            hld[cc * 2]     = __hip_atomic_load(sp,     __ATOMIC_RELAXED, __HIP_MEMORY_SCOPE_AGENT);
            hld[cc * 2 + 1] = __hip_atomic_load(sp + 1, __ATOMIC_RELAXED, __HIP_MEMORY_SCOPE_AGENT);
        }
        #pragma unroll
        for (int cc = 0; cc < 16; ++cc) {
            u64x2 v; v.x = hld[cc * 2]; v.y = hld[cc * 2 + 1];
            *(u64x2*)&hfrag[((size_t)cc * 256 + tid) * 8] = v;
        }
    }
    floatx4 accx;
    {
        const _Float16* xrow = xb + (size_t)bq * I + (l >> 4) * 8;
        floatx4 a = {0.f, 0.f, 0.f, 0.f};
        #pragma unroll
        for (int g = 0; g < 4; ++g) {        // 8-deep chunks: low VGPR peak
            uint4v xld[8];
            #pragma unroll
            for (int q = 0; q < 8; ++q)
                xld[q] = *(const uint4v*)(xrow + (g * 8 + q) * 32);
            #pragma unroll
            for (int q = 0; q < 8; ++q)
                a = __builtin_amdgcn_mfma_f32_16x16x32_f16(
                    __builtin_bit_cast(half8, wif[g * 8 + q]),
                    __builtin_bit_cast(half8, xld[q]), a, 0, 0, 0);
        }
        accx = a;
    }
    __syncthreads();   // hfrag(h0) ready

    int tm = 0;
    for (int t = 0; t < S; ++t) {
        // ---- h-chain from LDS frags ----
        floatx4 acch = {0.f, 0.f, 0.f, 0.f};
        #pragma unroll
        for (int kk = 0; kk < 32; ++kk) {
            half8 ah  = *(const half8*)&fragWh[rt * 16384 + kk * 512 + l * 8];
            half8 bhv = *(const half8*)&hfrag[(bt * 32 + kk) * 512 + l * 8];
            acch = __builtin_amdgcn_mfma_f32_16x16x32_f16(ah, bhv, acch, 0, 0, 0);
        }

        // ---- gates ----
        float pi = accx[0] + acch[0] + b0;
        float pf = accx[1] + acch[1] + b1;
        float po = accx[2] + acch[2] + b2;
        float pg = accx[3] + acch[3] + b3;

        float ig = 1.f / (1.f + __expf(-pi));
        float fg = 1.f / (1.f + __expf(-pf));
        float og = 1.f / (1.f + __expf(-po));
        float gg = 1.f - 2.f / (__expf(2.f * pg) + 1.f);

        c = c * fg + ig * gg;
        float th = 1.f - 2.f / (__expf(2.f * c) + 1.f);
        float ht = og * th;

        // ---- pack quad (shuffles pre-divergence) ----
        unsigned hb16 = (unsigned)__builtin_bit_cast(unsigned short, (_Float16)ht);
        unsigned p16 = (unsigned)__shfl_xor((int)hb16, 16);
        unsigned w0 = hb16 | (p16 << 16);
        unsigned long long p32 = (unsigned)__shfl_xor((int)w0, 32);
        unsigned long long w64 = (unsigned long long)w0 | (p32 << 32);
        float v1 = __shfl_xor(ht, 16);
        float v2 = __shfl_xor(ht, 32);
        float v3 = __shfl_xor(ht, 48);

        _Float16* hb_w = (tm == 0) ? hr1 : (tm == 1) ? hr2 : hr0;

        if (t == S - 1) {
            if ((l >> 4) == 0) {
                f32x4 o = {ht, v1, v2, v3};
                *(f32x4*)&out[((size_t)t * B + bq) * HD + jq] = o;
            }
            out[(size_t)S * B * HD + cix] = ht;                   // h_f
            out[(size_t)S * B * HD + (size_t)B * HD + cix] = c;   // c_f
            break;
        }

        // ---- RELEASE: exchange -> vmcnt(0) -> sync -> arrive ----
        if ((l >> 4) == 0) {
            unsigned long long* dst =
                (unsigned long long*)hb_w + ((size_t)bq * HD + jq) / 4;
            __hip_atomic_exchange(dst, w64, __ATOMIC_RELAXED,
                                  __HIP_MEMORY_SCOPE_AGENT);
        }
        asm volatile("s_waitcnt vmcnt(0)" ::: "memory");  // exchange at L3
        __syncthreads();                                   // whole block drained
        if (tid == 0)
            __hip_atomic_fetch_add(arr + (m >> 3) * ARRS, 1,
                                   __ATOMIC_RELAXED, __HIP_MEMORY_SCOPE_AGENT);

        // ---- out store AFTER arrive (ack off the release path) ----
        if ((l >> 4) == 0) {
            f32x4 o = {ht, v1, v2, v3};
            *(f32x4*)&out[((size_t)t * B + bq) * HD + jq] = o;
        }

        // ---- accx(t+1): chunked x loads + MFMA, overlaps the poll ----
        floatx4 accx_n;
        {
            const _Float16* xrow = xb + ((size_t)(t + 1) * B + bq) * I + (l >> 4) * 8;
            floatx4 a = {0.f, 0.f, 0.f, 0.f};
            #pragma unroll
            for (int g = 0; g < 4; ++g) {
                uint4v xld[8];
                #pragma unroll
                for (int q = 0; q < 8; ++q)
                    xld[q] = *(const uint4v*)(xrow + (g * 8 + q) * 32);
                #pragma unroll
                for (int q = 0; q < 8; ++q)
                    a = __builtin_amdgcn_mfma_f32_16x16x32_f16(
                        __builtin_bit_cast(half8, wif[g * 8 + q]),
                        __builtin_bit_cast(half8, xld[q]), a, 0, 0, 0);
            }
            accx_n = a;
        }

        // ---- poll: all 32 arrival lines in parallel ----
        if (w == 0) {
            const int target = 8 * (t + 1);
            int* ap = arr + (l & 31) * ARRS;
            while (!__all(__hip_atomic_load(ap, __ATOMIC_RELAXED,
                                            __HIP_MEMORY_SCOPE_AGENT) >= target))
                __builtin_amdgcn_s_sleep(1);
        }
        __syncthreads();   // h_{t+1} globally ready; hfrag no longer read

        // ---- stage h_{t+1} into hfrag (32 batch-issued agent u64 loads) ----
        {
            unsigned long long hld[32];
            #pragma unroll
            for (int cc = 0; cc < 16; ++cc) {
                int e = w + cc * 4;
                int kk = e & 31, btc = e >> 5;
                int bq_s = bg * 32 + btc * 16 + (l & 15);
                int k0 = (l >> 4) * 8 + kk * 32;
                const unsigned long long* sp =
                    (const unsigned long long*)hb_w + ((size_t)bq_s * HD + k0) / 4;
                hld[cc * 2]     = __hip_atomic_load(sp,     __ATOMIC_RELAXED, __HIP_MEMORY_SCOPE_AGENT);
                hld[cc * 2 + 1] = __hip_atomic_load(sp + 1, __ATOMIC_RELAXED, __HIP_MEMORY_SCOPE_AGENT);
            }
            #pragma unroll
            for (int cc = 0; cc < 16; ++cc) {
                u64x2 v; v.x = hld[cc * 2]; v.y = hld[cc * 2 + 1];
                *(u64x2*)&hfrag[((size_t)cc * 256 + tid) * 8] = v;
            }
        }
        accx = accx_n;
        __syncthreads();   // hfrag(h_{t+1}) ready
        tm = (tm == 2) ? 0 : tm + 1;
    }
}

// ---------- launch ----------

extern "C" void kernel_launch(void* const* d_in, const int* in_sizes, int n_in,
                              void* d_out, int out_size, void* d_ws, size_t ws_size,
                              hipStream_t stream) {
    const float* x  = (const float*)d_in[0];
    const float* h0 = (const float*)d_in[1];
    const float* c0 = (const float*)d_in[2];
    const float* Wi = (const float*)d_in[3];
    const float* bi = (const float*)d_in[4];
    const float* Wh = (const float*)d_in[5];
    const float* bh = (const float*)d_in[6];
    float* out = (float*)d_out;

    char* p = (char*)d_ws;
    _Float16* xb  = (_Float16*)p; p += (size_t)S * B * I * 2;
    _Float16* Wib = (_Float16*)p; p += (size_t)G4 * I * 2;
    _Float16* Whb = (_Float16*)p; p += (size_t)G4 * HD * 2;
    _Float16* hr0 = (_Float16*)p; p += (size_t)B * HD * 2;
    _Float16* hr1 = (_Float16*)p; p += (size_t)B * HD * 2;
    _Float16* hr2 = (_Float16*)p; p += (size_t)B * HD * 2;
    float* bsum   = (float*)p;    p += (size_t)G4 * 4;
    int* arr      = (int*)p;      p += 32 * ARRS * 4;

    long nx8 = (long)S * B * I / 8;
    cast_f32_to_f16<<<(int)((nx8 + 255) / 256), 256, 0, stream>>>(x, xb, nx8);
    long nw8 = (long)G4 * I / 8;
    cast_f32_to_f16<<<(int)((nw8 + 255) / 256), 256, 0, stream>>>(Wi, Wib, nw8);
    cast_f32_to_f16<<<(int)((nw8 + 255) / 256), 256, 0, stream>>>(Wh, Whb, nw8);
    init_state<<<(B * HD + 255) / 256, 256, 0, stream>>>(h0, bi, bh, hr0, bsum, arr);

    const float* c0p = c0;
    void* args[] = {(void*)&xb, (void*)&Wib, (void*)&Whb, (void*)&bsum,
                    (void*)&c0p, (void*)&hr0, (void*)&hr1, (void*)&hr2,
                    (void*)&out, (void*)&arr};
    hipError_t rc = hipLaunchCooperativeKernel((const void*)lstm_persistent,
                                               dim3(NB), dim3(256), args, 0, stream);
    if (rc != hipSuccess) {
        // Fallback: plain launch. 256 blocks at 1 block/CU on a 256-CU chip
        // are fully co-resident; the barrier is monotonic (no reset), so the
        // spin protocol remains safe.
        lstm_persistent<<<dim3(NB), dim3(256), 0, stream>>>(
            xb, Wib, Whb, bsum, c0p, hr0, hr1, hr2, out, arr);
    }
}